// Round 12
// baseline (247.584 us; speedup 1.0000x reference)
//
#include <hip/hip_runtime.h>
#include <hip/hip_bf16.h>

#define T_SEQ 2048
#define DIMD  1024
#define INNER 2048
#define STATE 64
#define BATCH 4
#define NCHUNK 64
#define CHUNK_L (T_SEQ / NCHUNK)   // 32
#define MROWS (BATCH * T_SEQ)      // 8192
#define PSTRIDE ((long)MROWS * STATE)

typedef __hip_bfloat16 bf16;
typedef __attribute__((ext_vector_type(8))) short bf16x8v;
typedef __attribute__((ext_vector_type(4))) float f32x4v;
typedef __attribute__((ext_vector_type(4))) short short4v;

__device__ __forceinline__ float b2f(short s) {
    unsigned u = ((unsigned)(unsigned short)s) << 16;
    float f;
    __builtin_memcpy(&f, &u, 4);
    return f;
}
__device__ __forceinline__ short f2b(float f) {
    bf16 h = __float2bfloat16(f);  // RNE
    short s;
    __builtin_memcpy(&s, &h, 2);
    return s;
}

// async global->LDS, 16B per lane. LDS dest must be lane-linear.
__device__ __forceinline__ void gld_lds16(void* lds, const void* gsrc) {
    __builtin_amdgcn_global_load_lds(
        (const __attribute__((address_space(1))) unsigned*)gsrc,
        (__attribute__((address_space(3))) unsigned*)lds, 16, 0, 0);
}

template<int N> __device__ __forceinline__ void waitcnt_vm() {
    if constexpr (N == 16)      asm volatile("s_waitcnt vmcnt(16)" ::: "memory");
    else if constexpr (N == 8)  asm volatile("s_waitcnt vmcnt(8)" ::: "memory");
    else if constexpr (N == 6)  asm volatile("s_waitcnt vmcnt(6)" ::: "memory");
    else if constexpr (N == 4)  asm volatile("s_waitcnt vmcnt(4)" ::: "memory");
    else if constexpr (N == 2)  asm volatile("s_waitcnt vmcnt(2)" ::: "memory");
    else                        asm volatile("s_waitcnt vmcnt(0)" ::: "memory");
}
__device__ __forceinline__ void block_barrier() {
    asm volatile("" ::: "memory");
    __builtin_amdgcn_s_barrier();
    asm volatile("" ::: "memory");
}

// Block swizzle. Mode 1: XCD contiguous-chunk (nwg%8==0). Mode 2: region —
// each XCD owns a gy/8-row strip, subdivided into 4x4-block regions so the
// ~4MB of A+B panels a region touches stays L2-resident and concurrent
// blocks share panel fetches. Requires gx%4==0, gy%8==0, (gy/8)%4==0 or
// region rows folding exactly (verified for launches used here).
template<int XSWZ>
__device__ __forceinline__ void swz_block(int& bx, int& by) {
    if constexpr (XSWZ == 1) {
        const int gx = gridDim.x;
        const int nwg = gx * gridDim.y;
        int id = by * gx + bx;
        const int cpx = nwg >> 3;
        id = (id & 7) * cpx + (id >> 3);
        bx = id % gx; by = id / gx;
    } else if constexpr (XSWZ == 2) {
        const int gx = gridDim.x;
        const int gy = gridDim.y;
        const int id = by * gx + bx;
        const int xcd = id & 7;
        const int c   = id >> 3;            // index within XCD strip
        const int rowsX = gy >> 3;          // strip height in blocks
        const int rw  = gx >> 2;            // regions per strip row (4-wide)
        const int r   = c >> 4;             // region index (16 blocks each)
        const int pos = c & 15;
        const int rbx = (r % rw) << 2;
        const int rby = (r / rw) << 2;
        bx = rbx + (pos & 3);
        by = xcd * rowsX + rby + (pos >> 2);
    }
}

// ---------------------------------------------------------------------------
// 8-phase 256^2 GEMM — depth-3 counted vmcnt at phase TOP (round-11 verified).
// See round-11 ledger. XOR swizzle: zero bank conflicts (round 6).
// ---------------------------------------------------------------------------
template<int EPI, int XSWZ>
__global__ __launch_bounds__(512, 2)
void gemm_8ph(const short* __restrict__ A, const short* __restrict__ B,
              void* __restrict__ Cout, int M, int N, int K)
{
    __shared__ __align__(16) short As[2][2][128 * 64];
    __shared__ __align__(16) short Bs[2][2][128 * 64];

    int bx = blockIdx.x, by = blockIdx.y;
    swz_block<XSWZ>(bx, by);

    const int tid  = threadIdx.x;
    const int lane = tid & 63;
    const int wave = tid >> 6;
    const int wm2 = (wave >> 2) & 1;        // 2 row-groups in a quadrant
    const int wn2 = wave & 3;               // 4 col-groups
    const long bm = (long)by * 256;
    const long bn = (long)bx * 256;

    const int rsel = lane & 15;
    const int ssrc = (((tid & 7) ^ ((tid >> 3) & 7)) * 8);
    const int swz  = lane & 7;

    f32x4v acc[4][4][2];                    // [quadrant][m][n]
#pragma unroll
    for (int q = 0; q < 4; q++)
#pragma unroll
        for (int m = 0; m < 4; m++)
#pragma unroll
            for (int n = 0; n < 2; n++)
                acc[q][m][n] = (f32x4v){0.f, 0.f, 0.f, 0.f};

    const int nt = K / 64;

    // stage half-tile h (0=A0,1=B0,2=A1,3=B1) of tile tt. 2 loads/thread.
    auto stage_half = [&](int tt, int h) {
        const int buf = tt & 1;
        const int half = h >> 1;
        const int k0 = tt * 64;
#pragma unroll
        for (int i = 0; i < 2; i++) {
            const int j = i * 512 + tid;    // slot in [128 rows][8 slots]
            if (h & 1)
                gld_lds16(&Bs[buf][half][j * 8],
                          &B[(bn + half * 128 + (j >> 3)) * (long)K + k0 + ssrc]);
            else
                gld_lds16(&As[buf][half][j * 8],
                          &A[(bm + half * 128 + (j >> 3)) * (long)K + k0 + ssrc]);
        }
    };

    stage_half(0, 0); stage_half(0, 1); stage_half(0, 2); stage_half(0, 3);

    for (int t = 0; t < nt; ++t) {
        const int buf = t & 1;
        const bool pf = (t + 1 < nt);
#pragma unroll
        for (int h = 0; h < 4; ++h) {
            if (pf) {
                if (h == 0) waitcnt_vm<4>();
                else if (h == 1) waitcnt_vm<4>();
                else if (h == 2) waitcnt_vm<4>();
            } else {
                if (h == 0) waitcnt_vm<4>();
                else if (h == 1) waitcnt_vm<2>();
                else if (h == 2) waitcnt_vm<0>();
            }
            block_barrier();

            const int QM[4] = {0, 1, 1, 0};
            const int QN[4] = {0, 0, 1, 1};
            const int qm = QM[h], qn = QN[h];
            bf16x8v af[4][2], bfv[2][2];
#pragma unroll
            for (int kkh = 0; kkh < 2; kkh++) {
                const int slog = kkh * 4 + (lane >> 4);
                const int soff = ((slog ^ swz) * 8);
#pragma unroll
                for (int m = 0; m < 4; m++) {
                    const int ar = wm2 * 64 + m * 16 + rsel;
                    af[m][kkh] = *(const bf16x8v*)&As[buf][qm][ar * 64 + soff];
                }
#pragma unroll
                for (int n = 0; n < 2; n++) {
                    const int br = wn2 * 32 + n * 16 + rsel;
                    bfv[n][kkh] = *(const bf16x8v*)&Bs[buf][qn][br * 64 + soff];
                }
            }
            if (pf) stage_half(t + 1, h);

            asm volatile("s_waitcnt lgkmcnt(0)" ::: "memory");
            __builtin_amdgcn_sched_barrier(0);   // rule 18
            __builtin_amdgcn_s_setprio(1);
#pragma unroll
            for (int kkh = 0; kkh < 2; kkh++)
#pragma unroll
                for (int m = 0; m < 4; m++)
#pragma unroll
                    for (int n = 0; n < 2; n++)
                        acc[h][m][n] = __builtin_amdgcn_mfma_f32_16x16x32_bf16(
                            af[m][kkh], bfv[n][kkh], acc[h][m][n], 0, 0, 0);
            __builtin_amdgcn_s_setprio(0);
        }
    }

#pragma unroll
    for (int q = 0; q < 4; q++) {
        const int QM[4] = {0, 1, 1, 0};
        const int QN[4] = {0, 0, 1, 1};
#pragma unroll
        for (int m = 0; m < 4; m++) {
#pragma unroll
            for (int n = 0; n < 2; n++) {
                const long col  = bn + QN[q] * 128 + wn2 * 32 + n * 16 + (lane & 15);
                const long row0 = bm + QM[q] * 128 + wm2 * 64 + m * 16 + (lane >> 4) * 4;
#pragma unroll
                for (int j = 0; j < 4; j++) {
                    const long idx = (row0 + j) * (long)N + col;
                    ((short*)Cout)[idx] = f2b(acc[q][m][n][j]);
                }
            }
        }
    }
}

// ---------------------------------------------------------------------------
// NT GEMM, ring-2 double-buffer with COUNTED vmcnt (round-8 verified config)
// ---------------------------------------------------------------------------
template<int BM, int BN, int BK, int WR, int WC, int EPI, int SPLITK, int XSWZ>
__global__ __launch_bounds__(WR*WC*64, 2)
void gemm_ring(const short* __restrict__ A, const short* __restrict__ B,
               void* __restrict__ Cout, int M, int N, int K,
               const short* __restrict__ u_ptr, const short* __restrict__ gate_ptr,
               const float* __restrict__ Dp)
{
    constexpr int MFR = BM / (WR * 16);
    constexpr int NFR = BN / (WC * 16);
    constexpr int THREADS = WR * WC * 64;
    constexpr int UPR = BK / 8;
    constexpr int AISS = (BM * UPR) / THREADS;
    constexpr int BISS = (BN * UPR) / THREADS;
    constexpr int LPS  = AISS + BISS;
    __shared__ __align__(16) short As[2][BM * BK];
    __shared__ __align__(16) short Bs[2][BN * BK];

    int bx = blockIdx.x, by = blockIdx.y;
    swz_block<XSWZ>(bx, by);

    const int tid  = threadIdx.x;
    const int lane = tid & 63;
    const int wave = tid >> 6;
    const int wm = (wave / WC) * (MFR * 16);
    const int wn = (wave % WC) * (NFR * 16);
    const long bm = (long)by * BM;
    const long bn = (long)bx * BN;

    f32x4v acc[MFR][NFR];
#pragma unroll
    for (int m = 0; m < MFR; m++)
#pragma unroll
        for (int n = 0; n < NFR; n++)
            acc[m][n] = (f32x4v){0.f, 0.f, 0.f, 0.f};

    const int rsel = lane & 15;
    const int ssrc = (((tid & 7) ^ ((tid >> 3) & 7)) * 8);
    const int swz  = lane & 7;

    int kbeg = 0, kend = K;
    if constexpr (SPLITK > 1) {
        const int kch = K / SPLITK;
        kbeg = blockIdx.z * kch;
        kend = kbeg + kch;
    }
    const int nt = (kend - kbeg) / BK;

    auto stage = [&](int buf, int k0) {
#pragma unroll
        for (int i = 0; i < AISS; i++) {
            const int j = i * THREADS + tid;
            gld_lds16(&As[buf][j * 8],
                      &A[(bm + (j >> 3)) * (long)K + k0 + ssrc]);
        }
#pragma unroll
        for (int i = 0; i < BISS; i++) {
            const int j = i * THREADS + tid;
            gld_lds16(&Bs[buf][j * 8],
                      &B[(bn + (j >> 3)) * (long)K + k0 + ssrc]);
        }
    };
    auto compute = [&](int buf) {
#pragma unroll
        for (int kk = 0; kk < BK; kk += 32) {
            const int slog = (kk >> 3) + (lane >> 4);
            const int soff = ((slog ^ swz) * 8);
            bf16x8v af[MFR], bfv[NFR];
#pragma unroll
            for (int m = 0; m < MFR; m++)
                af[m] = *(const bf16x8v*)&As[buf][(wm + m * 16 + rsel) * BK + soff];
#pragma unroll
            for (int n = 0; n < NFR; n++)
                bfv[n] = *(const bf16x8v*)&Bs[buf][(wn + n * 16 + rsel) * BK + soff];
#pragma unroll
            for (int m = 0; m < MFR; m++)
#pragma unroll
                for (int n = 0; n < NFR; n++)
                    acc[m][n] = __builtin_amdgcn_mfma_f32_16x16x32_bf16(
                        af[m], bfv[n], acc[m][n], 0, 0, 0);
        }
    };

    stage(0, kbeg);
    for (int t = 0; t < nt; ++t) {
        const bool pf = (t + 1 < nt);
        if (pf) stage((t + 1) & 1, kbeg + (t + 1) * BK);
        if (pf) waitcnt_vm<LPS>();
        else    waitcnt_vm<0>();
        block_barrier();
        compute(t & 1);
        block_barrier();
    }

    float* fout = (float*)Cout;
    if constexpr (SPLITK > 1)
        fout += (long)blockIdx.z * (long)M * N;

#pragma unroll
    for (int m = 0; m < MFR; m++) {
#pragma unroll
        for (int n = 0; n < NFR; n++) {
            const long col  = bn + wn + n * 16 + (lane & 15);
            const long row0 = bm + wm + m * 16 + (lane >> 4) * 4;
#pragma unroll
            for (int j = 0; j < 4; j++) {
                const long row = row0 + j;
                const float v = acc[m][n][j];
                const long idx = row * (long)N + col;
                if constexpr (EPI == 0) {
                    ((short*)Cout)[idx] = f2b(v);
                } else if constexpr (EPI == 1) {
                    fout[idx] = v;
                } else if constexpr (EPI == 2) {
                    float uv = b2f(u_ptr[row * (long)INNER + col]);
                    float gv = b2f(gate_ptr[row * (long)(2 * INNER) + col]);
                    float yv = v + Dp[col] * uv;
                    float sg = gv / (1.f + __expf(-gv));
                    ((short*)Cout)[idx] = f2b(yv * sg);
                } else {   // EPI == 3: + residual x, store bf16
                    ((short*)Cout)[idx] = f2b(v + b2f(u_ptr[idx]));
                }
            }
        }
    }
}

// ---------------------------------------------------------------------------
// depthwise causal conv1d(k=4, left-pad 3) + bias + SiLU
// ---------------------------------------------------------------------------
__global__ __launch_bounds__(256)
void conv_silu_kernel(const short* __restrict__ xproj, const float* __restrict__ cw,
                      const float* __restrict__ cb, short* __restrict__ u)
{
    const int bt = blockIdx.x;
    const int t  = bt & (T_SEQ - 1);
    const int c0 = threadIdx.x * 8;

    float wreg[4][8];
#pragma unroll
    for (int i = 0; i < 8; i++) {
        float4 wv = *(const float4*)&cw[(c0 + i) * 4];
        wreg[0][i] = wv.x; wreg[1][i] = wv.y; wreg[2][i] = wv.z; wreg[3][i] = wv.w;
    }
    float acc[8];
#pragma unroll
    for (int i = 0; i < 8; i++) acc[i] = cb[c0 + i];

#pragma unroll
    for (int k = 0; k < 4; k++) {
        if (t - 3 + k < 0) continue;
        bf16x8v v = *(const bf16x8v*)&xproj[(long)(bt - 3 + k) * (2 * INNER) + c0];
#pragma unroll
        for (int i = 0; i < 8; i++) acc[i] += b2f(v[i]) * wreg[k][i];
    }
    short o[8];
#pragma unroll
    for (int i = 0; i < 8; i++) {
        float s = acc[i] / (1.f + __expf(-acc[i]));
        o[i] = f2b(s);
    }
    *(bf16x8v*)&u[(long)bt * INNER + c0] = *(const bf16x8v*)o;
}

// ---------------------------------------------------------------------------
// Chunked parallel scan; Bu given as 4 split-K partials (stride PSTRIDE)
// ---------------------------------------------------------------------------
__global__ __launch_bounds__(64)
void scan_local_kernel(const float* __restrict__ Bu, float* __restrict__ locfin)
{
    const int b  = blockIdx.x / NCHUNK;
    const int ch = blockIdx.x % NCHUNK;
    const long base = ((long)b * T_SEQ + (long)ch * CHUNK_L) * STATE + threadIdx.x;
    float h = 0.f;
#pragma unroll
    for (int t = 0; t < CHUNK_L; t++) {
        const long o = base + (long)t * STATE;
        float bu = (Bu[o] + Bu[o + PSTRIDE]) + (Bu[o + 2 * PSTRIDE] + Bu[o + 3 * PSTRIDE]);
        h = 0.95f * h + 0.05f * bu;
    }
    locfin[(long)blockIdx.x * STATE + threadIdx.x] = h;
}

__global__ __launch_bounds__(256)
void carry_kernel(const float* __restrict__ locfin, float* __restrict__ carry,
                  float decayL)
{
    __shared__ float sm[BATCH * NCHUNK * STATE];   // 64 KB
    for (int i = threadIdx.x; i < BATCH * NCHUNK * STATE; i += 256)
        sm[i] = locfin[i];
    __syncthreads();
    const int b = threadIdx.x >> 6, s = threadIdx.x & 63;
    float c = 0.f;
    for (int ch = 0; ch < NCHUNK; ch++) {
        const int idx = (b * NCHUNK + ch) * STATE + s;
        carry[idx] = c;
        c = decayL * c + sm[idx];
    }
}

__global__ __launch_bounds__(64)
void scan_apply_kernel(const float* __restrict__ Bu, const float* __restrict__ carry,
                       short* __restrict__ hs)
{
    const int b  = blockIdx.x / NCHUNK;
    const int ch = blockIdx.x % NCHUNK;
    const long base = ((long)b * T_SEQ + (long)ch * CHUNK_L) * STATE + threadIdx.x;
    float h = carry[(long)blockIdx.x * STATE + threadIdx.x];
#pragma unroll
    for (int t = 0; t < CHUNK_L; t++) {
        const long o = base + (long)t * STATE;
        float bu = (Bu[o] + Bu[o + PSTRIDE]) + (Bu[o + 2 * PSTRIDE] + Bu[o + 3 * PSTRIDE]);
        h = 0.95f * h + 0.05f * bu;
        hs[o] = f2b(h);
    }
}

// ---------------------------------------------------------------------------
// LayerNorm over pre-summed bf16 (y + x) -> out (f32)
// ---------------------------------------------------------------------------
__global__ __launch_bounds__(256)
void ln_kernel(const short* __restrict__ yx, const float* __restrict__ g,
               const float* __restrict__ b, float* __restrict__ out)
{
    const int row = blockIdx.x;
    const int c   = threadIdx.x * 4;
    const long off = (long)row * DIMD + c;
    const short4v yv = *(const short4v*)&yx[off];
    float s0 = b2f(yv[0]), s1 = b2f(yv[1]), s2 = b2f(yv[2]), s3 = b2f(yv[3]);
    float sum = s0 + s1 + s2 + s3;
    float sq  = s0 * s0 + s1 * s1 + s2 * s2 + s3 * s3;
#pragma unroll
    for (int o = 32; o > 0; o >>= 1) {
        sum += __shfl_down(sum, o);
        sq  += __shfl_down(sq, o);
    }
    __shared__ float rs[4], rq[4];
    const int wave = threadIdx.x >> 6, lane = threadIdx.x & 63;
    if (lane == 0) { rs[wave] = sum; rq[wave] = sq; }
    __syncthreads();
    float tsum = rs[0] + rs[1] + rs[2] + rs[3];
    float tsq  = rq[0] + rq[1] + rq[2] + rq[3];
    float mu  = tsum * (1.f / DIMD);
    float inv = rsqrtf(tsq * (1.f / DIMD) - mu * mu + 1e-5f);
    float4 gv = *(const float4*)&g[c];
    float4 bv = *(const float4*)&b[c];
    float4 ov;
    ov.x = (s0 - mu) * inv * gv.x + bv.x;
    ov.y = (s1 - mu) * inv * gv.y + bv.y;
    ov.z = (s2 - mu) * inv * gv.z + bv.z;
    ov.w = (s3 - mu) * inv * gv.w + bv.w;
    *(float4*)&out[off] = ov;
}

// ---------------------------------------------------------------------------
// fused f32->bf16 convert of all 5 tensors into the contiguous ws region
// ---------------------------------------------------------------------------
#define C4_X   2097152L                       // 8192*1024/4
#define C4_W1  (C4_X + 1048576L)              // + 4096*1024/4
#define C4_WB  (C4_W1 + 32768L)               // + 64*2048/4
#define C4_WC  (C4_WB + 32768L)               // + 2048*64/4
#define C4_TOT (C4_WC + 524288L)              // + 1024*2048/4 = 3,735,552

__global__ __launch_bounds__(256)
void cvt5_kernel(const float* __restrict__ x, const float* __restrict__ w1,
                 const float* __restrict__ wB, const float* __restrict__ wC,
                 const float* __restrict__ wO, short* __restrict__ dst)
{
    const long i = (long)blockIdx.x * 256 + threadIdx.x;
    if (i >= C4_TOT) return;
    const float* s;
    long off;
    if      (i < C4_X)  { s = x;  off = i; }
    else if (i < C4_W1) { s = w1; off = i - C4_X; }
    else if (i < C4_WB) { s = wB; off = i - C4_W1; }
    else if (i < C4_WC) { s = wC; off = i - C4_WB; }
    else                { s = wO; off = i - C4_WC; }
    float4 v = *(const float4*)&s[off * 4];
    short4v o = { f2b(v.x), f2b(v.y), f2b(v.z), f2b(v.w) };
    *(short4v*)&dst[i * 4] = o;
}

extern "C" void kernel_launch(void* const* d_in, const int* in_sizes, int n_in,
                              void* d_out, int out_size, void* d_ws, size_t ws_size,
                              hipStream_t stream)
{
    const float* x     = (const float*)d_in[0];
    const float* W_in  = (const float*)d_in[1];
    const float* cw    = (const float*)d_in[2];
    const float* cb    = (const float*)d_in[3];
    const float* W_B   = (const float*)d_in[4];
    const float* W_C   = (const float*)d_in[5];
    const float* Dp    = (const float*)d_in[6];
    const float* W_out = (const float*)d_in[7];
    const float* ln_g  = (const float*)d_in[8];
    const float* ln_b  = (const float*)d_in[9];

    // workspace layout (bytes). total: 133,693,440 (~128 MB)
    char* p = (char*)d_ws;
    short* xw    = (short*)(p);                 // x bf16 [8192,1024] — LIVE until GEMM4
    short* w1    = (short*)(p +  16777216);     // W_in bf16 — dead after GEMM1
    short* wB    = (short*)(p +  25165824);     // W_B bf16  — dead after GEMM2
    short* wC    = (short*)(p +  25427968);     // W_C bf16  — read by GEMM3
    short* wO    = (short*)(p +  25690112);     // W_out bf16 — read by GEMM4
    short* xproj = (short*)(p +  29884416);     // x_proj bf16 [8192,4096]
    short* u     = (short*)(p +  96993280);     // u bf16 [8192,2048]
    short* hs    = (short*)(p + 132644864);     // hs bf16 [8192,64]
    short* yg    = u;                           // alias: in-place GEMM3 epilogue
    short* yx    = xproj;                       // GEMM4 out bf16(y+x), over dead xproj
    // scan/split-K scratch in DEAD regions (xw must survive for GEMM4 EPI=3):
    float* BuP    = (float*)(p + 16777216);     // 4x [8192,64] f32 = 8,388,608 (w1)
    float* locfin = (float*)(p + 25165824);     // 65,536 (wB region, dead post-GEMM2)
    float* carry  = (float*)(p + 25231360);     // 65,536

    const int M = MROWS;  // 8192

    // one fused convert for x, W_in, W_B, W_C, W_out (contiguous dst)
    cvt5_kernel<<<(int)((C4_TOT + 255) / 256), 256, 0, stream>>>(
        x, W_in, W_B, W_C, W_out, xw);

    // GEMM1: x_proj = x @ W_in^T  [8192,4096] bf16 — 8-phase + REGION swizzle
    gemm_8ph<0, 2><<<dim3(2 * INNER / 256, M / 256), 512, 0, stream>>>(
        xw, w1, xproj, M, 2 * INNER, DIMD);

    // conv + silu -> u
    conv_silu_kernel<<<M, 256, 0, stream>>>(xproj, cw, cb, u);

    // GEMM2: BuP[z] = u @ W_B^T partials  [4][8192, 64] f32 (split-K x4)
    gemm_ring<64, 64, 64, 2, 2, 1, 4, 0><<<dim3(1, M / 64, 4), 256, 0, stream>>>(
        u, wB, BuP, M, STATE, INNER, nullptr, nullptr, nullptr);

    // chunked parallel scan -> hs (bf16); sums the 4 partials on load
    float decayL;
    {
        double dd = 1.0;
        for (int i = 0; i < CHUNK_L; i++) dd *= 0.95;
        decayL = (float)dd;
    }
    scan_local_kernel<<<BATCH * NCHUNK, STATE, 0, stream>>>(BuP, locfin);
    carry_kernel<<<1, 256, 0, stream>>>(locfin, carry, decayL);
    scan_apply_kernel<<<BATCH * NCHUNK, STATE, 0, stream>>>(BuP, carry, hs);

    // GEMM3: y = hs @ W_C^T ; yg = (y + D*u) * silu(gate)   [8192, 2048] bf16
    gemm_ring<128, 128, 64, 2, 2, 2, 1, 1><<<dim3(INNER / 128, M / 128), 256, 0, stream>>>(
        hs, wC, yg, M, INNER, STATE, u, xproj + INNER, Dp);

    // GEMM4: yx = bf16(yg @ W_out^T + x)  [8192, 1024]
    // 256x128 tile (traffic 512->384 MB), 8 waves 64x64 each, region swizzle
    gemm_ring<256, 128, 64, 4, 2, 3, 1, 2><<<dim3(DIMD / 128, M / 256), 512, 0, stream>>>(
        yg, wO, yx, M, DIMD, INNER, xw, nullptr, nullptr);

    // LayerNorm(yx) -> d_out
    ln_kernel<<<M, 256, 0, stream>>>(yx, ln_g, ln_b, (float*)d_out);
}

// Round 13
// 242.800 us; speedup vs baseline: 1.0197x; 1.0197x over previous
//
#include <hip/hip_runtime.h>
#include <hip/hip_bf16.h>

#define T_SEQ 2048
#define DIMD  1024
#define INNER 2048
#define STATE 64
#define BATCH 4
#define NCHUNK 64
#define CHUNK_L (T_SEQ / NCHUNK)   // 32
#define MROWS (BATCH * T_SEQ)      // 8192
#define PSTRIDE ((long)MROWS * STATE)

typedef __hip_bfloat16 bf16;
typedef __attribute__((ext_vector_type(8))) short bf16x8v;
typedef __attribute__((ext_vector_type(4))) float f32x4v;
typedef __attribute__((ext_vector_type(4))) short short4v;

__device__ __forceinline__ float b2f(short s) {
    unsigned u = ((unsigned)(unsigned short)s) << 16;
    float f;
    __builtin_memcpy(&f, &u, 4);
    return f;
}
__device__ __forceinline__ short f2b(float f) {
    bf16 h = __float2bfloat16(f);  // RNE
    short s;
    __builtin_memcpy(&s, &h, 2);
    return s;
}

// async global->LDS, 16B per lane. LDS dest must be lane-linear.
__device__ __forceinline__ void gld_lds16(void* lds, const void* gsrc) {
    __builtin_amdgcn_global_load_lds(
        (const __attribute__((address_space(1))) unsigned*)gsrc,
        (__attribute__((address_space(3))) unsigned*)lds, 16, 0, 0);
}

template<int N> __device__ __forceinline__ void waitcnt_vm() {
    if constexpr (N == 16)      asm volatile("s_waitcnt vmcnt(16)" ::: "memory");
    else if constexpr (N == 8)  asm volatile("s_waitcnt vmcnt(8)" ::: "memory");
    else if constexpr (N == 6)  asm volatile("s_waitcnt vmcnt(6)" ::: "memory");
    else if constexpr (N == 4)  asm volatile("s_waitcnt vmcnt(4)" ::: "memory");
    else if constexpr (N == 2)  asm volatile("s_waitcnt vmcnt(2)" ::: "memory");
    else                        asm volatile("s_waitcnt vmcnt(0)" ::: "memory");
}
__device__ __forceinline__ void block_barrier() {
    asm volatile("" ::: "memory");
    __builtin_amdgcn_s_barrier();
    asm volatile("" ::: "memory");
}

// Block swizzle. Mode 1: XCD contiguous-chunk (nwg%8==0). Mode 2: region
// (4x4 blocks per region within an XCD strip; L2-resident panel sharing).
template<int XSWZ>
__device__ __forceinline__ void swz_block(int& bx, int& by) {
    if constexpr (XSWZ == 1) {
        const int gx = gridDim.x;
        const int nwg = gx * gridDim.y;
        int id = by * gx + bx;
        const int cpx = nwg >> 3;
        id = (id & 7) * cpx + (id >> 3);
        bx = id % gx; by = id / gx;
    } else if constexpr (XSWZ == 2) {
        const int gx = gridDim.x;
        const int gy = gridDim.y;
        const int id = by * gx + bx;
        const int xcd = id & 7;
        const int c   = id >> 3;
        const int rowsX = gy >> 3;
        const int rw  = gx >> 2;
        const int r   = c >> 4;
        const int pos = c & 15;
        const int rbx = (r % rw) << 2;
        const int rby = (r / rw) << 2;
        bx = rbx + (pos & 3);
        by = xcd * rowsX + rby + (pos >> 2);
    }
}

// ---------------------------------------------------------------------------
// 8-phase 256^2 GEMM — depth-3 counted vmcnt at phase TOP (round-11 ledger).
// ---------------------------------------------------------------------------
template<int EPI, int XSWZ>
__global__ __launch_bounds__(512, 2)
void gemm_8ph(const short* __restrict__ A, const short* __restrict__ B,
              void* __restrict__ Cout, int M, int N, int K)
{
    __shared__ __align__(16) short As[2][2][128 * 64];
    __shared__ __align__(16) short Bs[2][2][128 * 64];

    int bx = blockIdx.x, by = blockIdx.y;
    swz_block<XSWZ>(bx, by);

    const int tid  = threadIdx.x;
    const int lane = tid & 63;
    const int wave = tid >> 6;
    const int wm2 = (wave >> 2) & 1;
    const int wn2 = wave & 3;
    const long bm = (long)by * 256;
    const long bn = (long)bx * 256;

    const int rsel = lane & 15;
    const int ssrc = (((tid & 7) ^ ((tid >> 3) & 7)) * 8);
    const int swz  = lane & 7;

    f32x4v acc[4][4][2];
#pragma unroll
    for (int q = 0; q < 4; q++)
#pragma unroll
        for (int m = 0; m < 4; m++)
#pragma unroll
            for (int n = 0; n < 2; n++)
                acc[q][m][n] = (f32x4v){0.f, 0.f, 0.f, 0.f};

    const int nt = K / 64;

    auto stage_half = [&](int tt, int h) {
        const int buf = tt & 1;
        const int half = h >> 1;
        const int k0 = tt * 64;
#pragma unroll
        for (int i = 0; i < 2; i++) {
            const int j = i * 512 + tid;
            if (h & 1)
                gld_lds16(&Bs[buf][half][j * 8],
                          &B[(bn + half * 128 + (j >> 3)) * (long)K + k0 + ssrc]);
            else
                gld_lds16(&As[buf][half][j * 8],
                          &A[(bm + half * 128 + (j >> 3)) * (long)K + k0 + ssrc]);
        }
    };

    stage_half(0, 0); stage_half(0, 1); stage_half(0, 2); stage_half(0, 3);

    for (int t = 0; t < nt; ++t) {
        const int buf = t & 1;
        const bool pf = (t + 1 < nt);
#pragma unroll
        for (int h = 0; h < 4; ++h) {
            if (pf) {
                if (h == 0) waitcnt_vm<4>();
                else if (h == 1) waitcnt_vm<4>();
                else if (h == 2) waitcnt_vm<4>();
            } else {
                if (h == 0) waitcnt_vm<4>();
                else if (h == 1) waitcnt_vm<2>();
                else if (h == 2) waitcnt_vm<0>();
            }
            block_barrier();

            const int QM[4] = {0, 1, 1, 0};
            const int QN[4] = {0, 0, 1, 1};
            const int qm = QM[h], qn = QN[h];
            bf16x8v af[4][2], bfv[2][2];
#pragma unroll
            for (int kkh = 0; kkh < 2; kkh++) {
                const int slog = kkh * 4 + (lane >> 4);
                const int soff = ((slog ^ swz) * 8);
#pragma unroll
                for (int m = 0; m < 4; m++) {
                    const int ar = wm2 * 64 + m * 16 + rsel;
                    af[m][kkh] = *(const bf16x8v*)&As[buf][qm][ar * 64 + soff];
                }
#pragma unroll
                for (int n = 0; n < 2; n++) {
                    const int br = wn2 * 32 + n * 16 + rsel;
                    bfv[n][kkh] = *(const bf16x8v*)&Bs[buf][qn][br * 64 + soff];
                }
            }
            if (pf) stage_half(t + 1, h);

            asm volatile("s_waitcnt lgkmcnt(0)" ::: "memory");
            __builtin_amdgcn_sched_barrier(0);
            __builtin_amdgcn_s_setprio(1);
#pragma unroll
            for (int kkh = 0; kkh < 2; kkh++)
#pragma unroll
                for (int m = 0; m < 4; m++)
#pragma unroll
                    for (int n = 0; n < 2; n++)
                        acc[h][m][n] = __builtin_amdgcn_mfma_f32_16x16x32_bf16(
                            af[m][kkh], bfv[n][kkh], acc[h][m][n], 0, 0, 0);
            __builtin_amdgcn_s_setprio(0);
        }
    }

#pragma unroll
    for (int q = 0; q < 4; q++) {
        const int QM[4] = {0, 1, 1, 0};
        const int QN[4] = {0, 0, 1, 1};
#pragma unroll
        for (int m = 0; m < 4; m++) {
#pragma unroll
            for (int n = 0; n < 2; n++) {
                const long col  = bn + QN[q] * 128 + wn2 * 32 + n * 16 + (lane & 15);
                const long row0 = bm + QM[q] * 128 + wm2 * 64 + m * 16 + (lane >> 4) * 4;
#pragma unroll
                for (int j = 0; j < 4; j++) {
                    const long idx = (row0 + j) * (long)N + col;
                    ((short*)Cout)[idx] = f2b(acc[q][m][n][j]);
                }
            }
        }
    }
}

// ---------------------------------------------------------------------------
// NT GEMM, ring-2 double-buffer with COUNTED vmcnt (round-8 verified config)
// ---------------------------------------------------------------------------
template<int BM, int BN, int BK, int WR, int WC, int EPI, int SPLITK, int XSWZ>
__global__ __launch_bounds__(WR*WC*64, 2)
void gemm_ring(const short* __restrict__ A, const short* __restrict__ B,
               void* __restrict__ Cout, int M, int N, int K,
               const short* __restrict__ u_ptr, const short* __restrict__ gate_ptr,
               const float* __restrict__ Dp)
{
    constexpr int MFR = BM / (WR * 16);
    constexpr int NFR = BN / (WC * 16);
    constexpr int THREADS = WR * WC * 64;
    constexpr int UPR = BK / 8;
    constexpr int AISS = (BM * UPR) / THREADS;
    constexpr int BISS = (BN * UPR) / THREADS;
    constexpr int LPS  = AISS + BISS;
    __shared__ __align__(16) short As[2][BM * BK];
    __shared__ __align__(16) short Bs[2][BN * BK];

    int bx = blockIdx.x, by = blockIdx.y;
    swz_block<XSWZ>(bx, by);

    const int tid  = threadIdx.x;
    const int lane = tid & 63;
    const int wave = tid >> 6;
    const int wm = (wave / WC) * (MFR * 16);
    const int wn = (wave % WC) * (NFR * 16);
    const long bm = (long)by * BM;
    const long bn = (long)bx * BN;

    f32x4v acc[MFR][NFR];
#pragma unroll
    for (int m = 0; m < MFR; m++)
#pragma unroll
        for (int n = 0; n < NFR; n++)
            acc[m][n] = (f32x4v){0.f, 0.f, 0.f, 0.f};

    const int rsel = lane & 15;
    const int ssrc = (((tid & 7) ^ ((tid >> 3) & 7)) * 8);
    const int swz  = lane & 7;

    int kbeg = 0, kend = K;
    if constexpr (SPLITK > 1) {
        const int kch = K / SPLITK;
        kbeg = blockIdx.z * kch;
        kend = kbeg + kch;
    }
    const int nt = (kend - kbeg) / BK;

    auto stage = [&](int buf, int k0) {
#pragma unroll
        for (int i = 0; i < AISS; i++) {
            const int j = i * THREADS + tid;
            gld_lds16(&As[buf][j * 8],
                      &A[(bm + (j >> 3)) * (long)K + k0 + ssrc]);
        }
#pragma unroll
        for (int i = 0; i < BISS; i++) {
            const int j = i * THREADS + tid;
            gld_lds16(&Bs[buf][j * 8],
                      &B[(bn + (j >> 3)) * (long)K + k0 + ssrc]);
        }
    };
    auto compute = [&](int buf) {
#pragma unroll
        for (int kk = 0; kk < BK; kk += 32) {
            const int slog = (kk >> 3) + (lane >> 4);
            const int soff = ((slog ^ swz) * 8);
            bf16x8v af[MFR], bfv[NFR];
#pragma unroll
            for (int m = 0; m < MFR; m++)
                af[m] = *(const bf16x8v*)&As[buf][(wm + m * 16 + rsel) * BK + soff];
#pragma unroll
            for (int n = 0; n < NFR; n++)
                bfv[n] = *(const bf16x8v*)&Bs[buf][(wn + n * 16 + rsel) * BK + soff];
#pragma unroll
            for (int m = 0; m < MFR; m++)
#pragma unroll
                for (int n = 0; n < NFR; n++)
                    acc[m][n] = __builtin_amdgcn_mfma_f32_16x16x32_bf16(
                        af[m], bfv[n], acc[m][n], 0, 0, 0);
        }
    };

    stage(0, kbeg);
    for (int t = 0; t < nt; ++t) {
        const bool pf = (t + 1 < nt);
        if (pf) stage((t + 1) & 1, kbeg + (t + 1) * BK);
        if (pf) waitcnt_vm<LPS>();
        else    waitcnt_vm<0>();
        block_barrier();
        compute(t & 1);
        block_barrier();
    }

    float* fout = (float*)Cout;
    if constexpr (SPLITK > 1)
        fout += (long)blockIdx.z * (long)M * N;

#pragma unroll
    for (int m = 0; m < MFR; m++) {
#pragma unroll
        for (int n = 0; n < NFR; n++) {
            const long col  = bn + wn + n * 16 + (lane & 15);
            const long row0 = bm + wm + m * 16 + (lane >> 4) * 4;
#pragma unroll
            for (int j = 0; j < 4; j++) {
                const long row = row0 + j;
                const float v = acc[m][n][j];
                const long idx = row * (long)N + col;
                if constexpr (EPI == 0) {
                    ((short*)Cout)[idx] = f2b(v);
                } else if constexpr (EPI == 1) {
                    fout[idx] = v;
                } else {   // EPI == 3: + residual x, store bf16
                    ((short*)Cout)[idx] = f2b(v + b2f(u_ptr[idx]));
                }
            }
        }
    }
}

// ---------------------------------------------------------------------------
// GEMM3 fused (K=64, nt=1): y = hs @ W_C^T; yg = (y + D*u) * silu(gate).
// Single-buffer MFMA (128x128 tile, 4 waves), then LDS-staged epilogue:
// acc -> padded f32 LDS (2 row-half passes, write in fragment layout =
// 2-way conflicts only), vector-read rows, 16B u/gate loads, 16B yg store.
// In-place u->yg safe: same thread reads u[row][c..c+7] then writes it.
// ---------------------------------------------------------------------------
#define EBS 132   // f32 row stride in epilogue LDS (128 + 4 pad, 16B aligned)
__global__ __launch_bounds__(256, 2)
void gemm3_fused(const short* __restrict__ hs, const short* __restrict__ Wc,
                 short* __restrict__ yg, const short* __restrict__ gate_ptr,
                 const float* __restrict__ Dp)
{
    __shared__ __align__(16) short As[128 * 64];
    __shared__ __align__(16) short Bs[128 * 64];
    __shared__ __align__(16) float eb[64 * EBS];   // 33,792 B

    const int tid  = threadIdx.x;
    const int lane = tid & 63;
    const int wave = tid >> 6;
    const int wm = (wave >> 1) * 64;    // 2x2 waves, 64x64 each
    const int wn = (wave & 1) * 64;
    const long bm = (long)blockIdx.y * 128;
    const long bn = (long)blockIdx.x * 128;

    const int rsel = lane & 15;
    const int ssrc = (((tid & 7) ^ ((tid >> 3) & 7)) * 8);
    const int swz  = lane & 7;

    // stage A=hs[128x64], B=Wc[128x64] (single buffer; K=64 is one tile)
#pragma unroll
    for (int i = 0; i < 4; i++) {
        const int j = i * 256 + tid;
        gld_lds16(&As[j * 8], &hs[(bm + (j >> 3)) * (long)STATE + ssrc]);
    }
#pragma unroll
    for (int i = 0; i < 4; i++) {
        const int j = i * 256 + tid;
        gld_lds16(&Bs[j * 8], &Wc[(bn + (j >> 3)) * (long)STATE + ssrc]);
    }
    waitcnt_vm<0>();
    block_barrier();

    f32x4v acc[4][4];
#pragma unroll
    for (int m = 0; m < 4; m++)
#pragma unroll
        for (int n = 0; n < 4; n++)
            acc[m][n] = (f32x4v){0.f, 0.f, 0.f, 0.f};

#pragma unroll
    for (int kk = 0; kk < 64; kk += 32) {
        const int slog = (kk >> 3) + (lane >> 4);
        const int soff = ((slog ^ swz) * 8);
        bf16x8v af[4], bfv[4];
#pragma unroll
        for (int m = 0; m < 4; m++)
            af[m] = *(const bf16x8v*)&As[(wm + m * 16 + rsel) * 64 + soff];
#pragma unroll
        for (int n = 0; n < 4; n++)
            bfv[n] = *(const bf16x8v*)&Bs[(wn + n * 16 + rsel) * 64 + soff];
#pragma unroll
        for (int m = 0; m < 4; m++)
#pragma unroll
            for (int n = 0; n < 4; n++)
                acc[m][n] = __builtin_amdgcn_mfma_f32_16x16x32_bf16(
                    af[m], bfv[n], acc[m][n], 0, 0, 0);
    }

    // epilogue: 2 passes over row-halves of the 128x128 tile
#pragma unroll
    for (int p = 0; p < 2; p++) {
        block_barrier();
        if ((wm >> 6) == p) {           // waves owning rows [64p, 64p+64)
#pragma unroll
            for (int m = 0; m < 4; m++) {
#pragma unroll
                for (int n = 0; n < 4; n++) {
                    const int cl = wn + n * 16 + (lane & 15);
#pragma unroll
                    for (int j = 0; j < 4; j++) {
                        const int rl = m * 16 + (lane >> 4) * 4 + j; // 0..63
                        eb[rl * EBS + cl] = acc[m][n][j];
                    }
                }
            }
        }
        block_barrier();
        // 64 rows x 16 col-groups = 1024 units / 256 threads
#pragma unroll
        for (int k = 0; k < 4; k++) {
            const int unit = k * 256 + tid;
            const int rl = unit >> 4, cg = (unit & 15) * 8;
            const long grow = bm + p * 64 + rl;
            const long gcol = bn + cg;
            f32x4v y0 = *(const f32x4v*)&eb[rl * EBS + cg];
            f32x4v y1 = *(const f32x4v*)&eb[rl * EBS + cg + 4];
            bf16x8v uv = *(const bf16x8v*)&yg[grow * (long)INNER + gcol];
            bf16x8v gv = *(const bf16x8v*)&gate_ptr[grow * (long)(2 * INNER) + gcol];
            short o[8];
#pragma unroll
            for (int i = 0; i < 8; i++) {
                const float yy = (i < 4 ? y0[i] : y1[i - 4]);
                const float uu = b2f(uv[i]);
                const float gg = b2f(gv[i]);
                const float yv = yy + Dp[gcol + i] * uu;
                const float sg = gg / (1.f + __expf(-gg));
                o[i] = f2b(yv * sg);
            }
            *(bf16x8v*)&yg[grow * (long)INNER + gcol] = *(const bf16x8v*)o;
        }
    }
}

// ---------------------------------------------------------------------------
// depthwise causal conv1d(k=4, left-pad 3) + bias + SiLU
// ---------------------------------------------------------------------------
__global__ __launch_bounds__(256)
void conv_silu_kernel(const short* __restrict__ xproj, const float* __restrict__ cw,
                      const float* __restrict__ cb, short* __restrict__ u)
{
    const int bt = blockIdx.x;
    const int t  = bt & (T_SEQ - 1);
    const int c0 = threadIdx.x * 8;

    float wreg[4][8];
#pragma unroll
    for (int i = 0; i < 8; i++) {
        float4 wv = *(const float4*)&cw[(c0 + i) * 4];
        wreg[0][i] = wv.x; wreg[1][i] = wv.y; wreg[2][i] = wv.z; wreg[3][i] = wv.w;
    }
    float acc[8];
#pragma unroll
    for (int i = 0; i < 8; i++) acc[i] = cb[c0 + i];

#pragma unroll
    for (int k = 0; k < 4; k++) {
        if (t - 3 + k < 0) continue;
        bf16x8v v = *(const bf16x8v*)&xproj[(long)(bt - 3 + k) * (2 * INNER) + c0];
#pragma unroll
        for (int i = 0; i < 8; i++) acc[i] += b2f(v[i]) * wreg[k][i];
    }
    short o[8];
#pragma unroll
    for (int i = 0; i < 8; i++) {
        float s = acc[i] / (1.f + __expf(-acc[i]));
        o[i] = f2b(s);
    }
    *(bf16x8v*)&u[(long)bt * INNER + c0] = *(const bf16x8v*)o;
}

// ---------------------------------------------------------------------------
// Chunked parallel scan; Bu given as 4 split-K partials (stride PSTRIDE)
// ---------------------------------------------------------------------------
__global__ __launch_bounds__(64)
void scan_local_kernel(const float* __restrict__ Bu, float* __restrict__ locfin)
{
    const int b  = blockIdx.x / NCHUNK;
    const int ch = blockIdx.x % NCHUNK;
    const long base = ((long)b * T_SEQ + (long)ch * CHUNK_L) * STATE + threadIdx.x;
    float h = 0.f;
#pragma unroll
    for (int t = 0; t < CHUNK_L; t++) {
        const long o = base + (long)t * STATE;
        float bu = (Bu[o] + Bu[o + PSTRIDE]) + (Bu[o + 2 * PSTRIDE] + Bu[o + 3 * PSTRIDE]);
        h = 0.95f * h + 0.05f * bu;
    }
    locfin[(long)blockIdx.x * STATE + threadIdx.x] = h;
}

__global__ __launch_bounds__(256)
void carry_kernel(const float* __restrict__ locfin, float* __restrict__ carry,
                  float decayL)
{
    __shared__ float sm[BATCH * NCHUNK * STATE];   // 64 KB
    for (int i = threadIdx.x; i < BATCH * NCHUNK * STATE; i += 256)
        sm[i] = locfin[i];
    __syncthreads();
    const int b = threadIdx.x >> 6, s = threadIdx.x & 63;
    float c = 0.f;
    for (int ch = 0; ch < NCHUNK; ch++) {
        const int idx = (b * NCHUNK + ch) * STATE + s;
        carry[idx] = c;
        c = decayL * c + sm[idx];
    }
}

__global__ __launch_bounds__(64)
void scan_apply_kernel(const float* __restrict__ Bu, const float* __restrict__ carry,
                       short* __restrict__ hs)
{
    const int b  = blockIdx.x / NCHUNK;
    const int ch = blockIdx.x % NCHUNK;
    const long base = ((long)b * T_SEQ + (long)ch * CHUNK_L) * STATE + threadIdx.x;
    float h = carry[(long)blockIdx.x * STATE + threadIdx.x];
#pragma unroll
    for (int t = 0; t < CHUNK_L; t++) {
        const long o = base + (long)t * STATE;
        float bu = (Bu[o] + Bu[o + PSTRIDE]) + (Bu[o + 2 * PSTRIDE] + Bu[o + 3 * PSTRIDE]);
        h = 0.95f * h + 0.05f * bu;
        hs[o] = f2b(h);
    }
}

// ---------------------------------------------------------------------------
// LayerNorm over pre-summed bf16 (y + x) -> out (f32)
// ---------------------------------------------------------------------------
__global__ __launch_bounds__(256)
void ln_kernel(const short* __restrict__ yx, const float* __restrict__ g,
               const float* __restrict__ b, float* __restrict__ out)
{
    const int row = blockIdx.x;
    const int c   = threadIdx.x * 4;
    const long off = (long)row * DIMD + c;
    const short4v yv = *(const short4v*)&yx[off];
    float s0 = b2f(yv[0]), s1 = b2f(yv[1]), s2 = b2f(yv[2]), s3 = b2f(yv[3]);
    float sum = s0 + s1 + s2 + s3;
    float sq  = s0 * s0 + s1 * s1 + s2 * s2 + s3 * s3;
#pragma unroll
    for (int o = 32; o > 0; o >>= 1) {
        sum += __shfl_down(sum, o);
        sq  += __shfl_down(sq, o);
    }
    __shared__ float rs[4], rq[4];
    const int wave = threadIdx.x >> 6, lane = threadIdx.x & 63;
    if (lane == 0) { rs[wave] = sum; rq[wave] = sq; }
    __syncthreads();
    float tsum = rs[0] + rs[1] + rs[2] + rs[3];
    float tsq  = rq[0] + rq[1] + rq[2] + rq[3];
    float mu  = tsum * (1.f / DIMD);
    float inv = rsqrtf(tsq * (1.f / DIMD) - mu * mu + 1e-5f);
    float4 gv = *(const float4*)&g[c];
    float4 bv = *(const float4*)&b[c];
    float4 ov;
    ov.x = (s0 - mu) * inv * gv.x + bv.x;
    ov.y = (s1 - mu) * inv * gv.y + bv.y;
    ov.z = (s2 - mu) * inv * gv.z + bv.z;
    ov.w = (s3 - mu) * inv * gv.w + bv.w;
    *(float4*)&out[off] = ov;
}

// ---------------------------------------------------------------------------
// fused f32->bf16 convert of all 5 tensors into the contiguous ws region
// ---------------------------------------------------------------------------
#define C4_X   2097152L                       // 8192*1024/4
#define C4_W1  (C4_X + 1048576L)              // + 4096*1024/4
#define C4_WB  (C4_W1 + 32768L)               // + 64*2048/4
#define C4_WC  (C4_WB + 32768L)               // + 2048*64/4
#define C4_TOT (C4_WC + 524288L)              // + 1024*2048/4 = 3,735,552

__global__ __launch_bounds__(256)
void cvt5_kernel(const float* __restrict__ x, const float* __restrict__ w1,
                 const float* __restrict__ wB, const float* __restrict__ wC,
                 const float* __restrict__ wO, short* __restrict__ dst)
{
    const long i = (long)blockIdx.x * 256 + threadIdx.x;
    if (i >= C4_TOT) return;
    const float* s;
    long off;
    if      (i < C4_X)  { s = x;  off = i; }
    else if (i < C4_W1) { s = w1; off = i - C4_X; }
    else if (i < C4_WB) { s = wB; off = i - C4_W1; }
    else if (i < C4_WC) { s = wC; off = i - C4_WB; }
    else                { s = wO; off = i - C4_WC; }
    float4 v = *(const float4*)&s[off * 4];
    short4v o = { f2b(v.x), f2b(v.y), f2b(v.z), f2b(v.w) };
    *(short4v*)&dst[i * 4] = o;
}

extern "C" void kernel_launch(void* const* d_in, const int* in_sizes, int n_in,
                              void* d_out, int out_size, void* d_ws, size_t ws_size,
                              hipStream_t stream)
{
    const float* x     = (const float*)d_in[0];
    const float* W_in  = (const float*)d_in[1];
    const float* cw    = (const float*)d_in[2];
    const float* cb    = (const float*)d_in[3];
    const float* W_B   = (const float*)d_in[4];
    const float* W_C   = (const float*)d_in[5];
    const float* Dp    = (const float*)d_in[6];
    const float* W_out = (const float*)d_in[7];
    const float* ln_g  = (const float*)d_in[8];
    const float* ln_b  = (const float*)d_in[9];

    // workspace layout (bytes). total: 133,693,440 (~128 MB)
    char* p = (char*)d_ws;
    short* xw    = (short*)(p);                 // x bf16 [8192,1024] — LIVE until GEMM4
    short* w1    = (short*)(p +  16777216);     // W_in bf16 — dead after GEMM1
    short* wB    = (short*)(p +  25165824);     // W_B bf16  — dead after GEMM2
    short* wC    = (short*)(p +  25427968);     // W_C bf16  — read by GEMM3
    short* wO    = (short*)(p +  25690112);     // W_out bf16 — read by GEMM4
    short* xproj = (short*)(p +  29884416);     // x_proj bf16 [8192,4096]
    short* u     = (short*)(p +  96993280);     // u bf16 [8192,2048]
    short* hs    = (short*)(p + 132644864);     // hs bf16 [8192,64]
    short* yg    = u;                           // alias: in-place GEMM3 epilogue
    short* yx    = xproj;                       // GEMM4 out bf16(y+x), over dead xproj
    // scan/split-K scratch in DEAD regions (xw must survive for GEMM4 EPI=3):
    float* BuP    = (float*)(p + 16777216);     // 4x [8192,64] f32 = 8,388,608 (w1)
    float* locfin = (float*)(p + 25165824);     // 65,536 (wB region, dead post-GEMM2)
    float* carry  = (float*)(p + 25231360);     // 65,536

    const int M = MROWS;  // 8192

    // one fused convert for x, W_in, W_B, W_C, W_out (contiguous dst)
    cvt5_kernel<<<(int)((C4_TOT + 255) / 256), 256, 0, stream>>>(
        x, W_in, W_B, W_C, W_out, xw);

    // GEMM1: x_proj = x @ W_in^T  [8192,4096] bf16 — 8-phase + region swizzle
    gemm_8ph<0, 2><<<dim3(2 * INNER / 256, M / 256), 512, 0, stream>>>(
        xw, w1, xproj, M, 2 * INNER, DIMD);

    // conv + silu -> u
    conv_silu_kernel<<<M, 256, 0, stream>>>(xproj, cw, cb, u);

    // GEMM2: BuP[z] = u @ W_B^T partials  [4][8192, 64] f32 (split-K x4)
    gemm_ring<64, 64, 64, 2, 2, 1, 4, 0><<<dim3(1, M / 64, 4), 256, 0, stream>>>(
        u, wB, BuP, M, STATE, INNER, nullptr, nullptr, nullptr);

    // chunked parallel scan -> hs (bf16); sums the 4 partials on load
    float decayL;
    {
        double dd = 1.0;
        for (int i = 0; i < CHUNK_L; i++) dd *= 0.95;
        decayL = (float)dd;
    }
    scan_local_kernel<<<BATCH * NCHUNK, STATE, 0, stream>>>(BuP, locfin);
    carry_kernel<<<1, 256, 0, stream>>>(locfin, carry, decayL);
    scan_apply_kernel<<<BATCH * NCHUNK, STATE, 0, stream>>>(BuP, carry, hs);

    // GEMM3 fused: yg = (hs @ W_C^T + D*u) * silu(gate)  [8192, 2048] bf16
    gemm3_fused<<<dim3(INNER / 128, M / 128), 256, 0, stream>>>(
        hs, wC, yg, xproj + INNER, Dp);

    // GEMM4: yx = bf16(yg @ W_out^T + x)  [8192,1024] — round-8 proven config
    gemm_ring<128, 128, 64, 2, 2, 3, 1, 1><<<dim3(DIMD / 128, M / 128), 256, 0, stream>>>(
        yg, wO, yx, M, DIMD, INNER, xw, nullptr, nullptr);

    // LayerNorm(yx) -> d_out
    ln_kernel<<<M, 256, 0, stream>>>(yx, ln_g, ln_b, (float*)d_out);
}